// Round 4
// baseline (1673.979 us; speedup 1.0000x reference)
//
#include <hip/hip_runtime.h>

#define EPSF 1e-5f
#define DECAYF 0.99f
#define KCODES 2048
#define DIM 256
#define TT 96          // 8 code-tiles x 12 virtual K-tiles (K=768 / 64)

typedef _Float16 f16;
typedef f16 f16x8 __attribute__((ext_vector_type(8)));
typedef float f32x4 __attribute__((ext_vector_type(4)));

#define MFMA16(A, B, C) __builtin_amdgcn_mfma_f32_16x16x32_f16(A, B, C, 0, 0, 0)

__device__ __forceinline__ void gload_lds16(const void* g, void* l) {
    __builtin_amdgcn_global_load_lds(
        (const __attribute__((address_space(1))) void*)g,
        (__attribute__((address_space(3))) void*)l, 16, 0, 0);
}

// ---------------------------------------------------------------------------
// split_x: xh = (f16)x, xl = (f16)(x - xh)
// ---------------------------------------------------------------------------
__global__ __launch_bounds__(256) void split_x_kernel(
    const float* __restrict__ x, f16* __restrict__ xh, f16* __restrict__ xl, int n8)
{
    int i = blockIdx.x * 256 + threadIdx.x;
    if (i >= n8) return;
    f32x4 v0 = ((const f32x4*)x)[2 * i];
    f32x4 v1 = ((const f32x4*)x)[2 * i + 1];
    f16x8 h, l;
    #pragma unroll
    for (int t = 0; t < 4; ++t) {
        f16 h0 = (f16)v0[t]; h[t] = h0; l[t] = (f16)(v0[t] - (float)h0);
        f16 h1 = (f16)v1[t]; h[t + 4] = h1; l[t + 4] = (f16)(v1[t] - (float)h1);
    }
    ((f16x8*)xh)[i] = h;
    ((f16x8*)xl)[i] = l;
}

// ---------------------------------------------------------------------------
// prep: embed = embed_sum / clamp(usage); e2 = ||embed||^2; eh/el f16 split
// ---------------------------------------------------------------------------
__global__ __launch_bounds__(256) void prep_embed_kernel(
    const float* __restrict__ embed_sum, const float* __restrict__ usage,
    float* __restrict__ embed, f16* __restrict__ eh, f16* __restrict__ el,
    float* __restrict__ e2)
{
    int k = blockIdx.x;
    int d = threadIdx.x;
    float inv = 1.0f / fmaxf(usage[k], EPSF);
    float e = embed_sum[k * DIM + d] * inv;
    embed[k * DIM + d] = e;
    float ec = fminf(fmaxf(e, -65000.0f), 65000.0f);
    f16 h = (f16)ec;
    f16 l = (f16)(ec - (float)h);
    eh[k * DIM + d] = h;
    el[k * DIM + d] = l;
    float sq = e * e;
    #pragma unroll
    for (int off = 32; off > 0; off >>= 1) sq += __shfl_down(sq, off, 64);
    __shared__ float ws[4];
    if ((threadIdx.x & 63) == 0) ws[threadIdx.x >> 6] = sq;
    __syncthreads();
    if (threadIdx.x == 0) e2[k] = ws[0] + ws[1] + ws[2] + ws[3];
}

// ---------------------------------------------------------------------------
// argmin: 8-phase-style pipelined f16 GEMM-argmin.
// BM=256 x BN=256, BK=64, 8 waves (4M x 2N, wave tile 64x128), 2 dbuf.
// Per K-tile: 4 phases of 16 MFMA; 1 staged 16KB unit per phase;
// counted vmcnt(4)@p0 / vmcnt(8)@p3; XOR-swizzled LDS (conflict-free b128),
// swizzle applied via pre-swizzled global source (gload_lds writes linear).
// ---------------------------------------------------------------------------
__global__ __launch_bounds__(512, 2) void argmin_kernel(
    const f16* __restrict__ xh, const f16* __restrict__ xl,
    const f16* __restrict__ eh, const f16* __restrict__ el,
    const float* __restrict__ e2, int* __restrict__ flat_ind, int* __restrict__ cnt)
{
    // buffer d at d*65536: A [2kh][256r][4g]*16B (32KB), B [2qc][2kh][128c][4g]*16B (32KB)
    __shared__ __align__(1024) char lds[2 * 65536 + 8192];
    float* e2s = (float*)(lds + 131072);

    const int tid  = threadIdx.x;
    const int w    = tid >> 6, lane = tid & 63;
    const int l15  = lane & 15, l4 = lane >> 4;
    const int wm   = w >> 1, wn = w & 1;
    const int row0 = blockIdx.x * 256;
    const int gsw  = (lane & 3) ^ ((lane >> 2) & 3);   // inverse-swizzle granule
    const int lq   = lane >> 2;                        // 0..15
    const int slot16 = (l4 ^ (l15 & 3)) * 16;          // swizzled read slot

    f32x4 acc[4][8];
    f16x8 a[4], bfr[4];
    float best[16];
    int   bidx[16];
    #pragma unroll
    for (int t = 0; t < 16; ++t) { best[t] = 3.4e38f; bidx[t] = 0; }

    auto segA = [&](int s_) { return (s_ < 8) ? xh : xl; };
    auto segB = [&](int s_) { return (s_ >= 4 && s_ < 8) ? el : eh; };

    auto stageA = [&](int kh, int s_, int buf) {
        const f16* A = segA(s_);
        const int koff = (s_ & 3) * 64 + kh * 32;
        char* dst = lds + buf * 65536 + kh * 16384 + w * 2048;
        #pragma unroll
        for (int q = 0; q < 2; ++q) {
            const int row = w * 32 + q * 16 + lq;
            const f16* src = A + (size_t)(row0 + row) * DIM + koff + gsw * 8;
            gload_lds16(src, dst + q * 1024);
        }
    };
    auto stageB = [&](int qc, int c_, int s_, int buf) {
        const f16* B = segB(s_);
        const int koff = (s_ & 3) * 64;
        char* dstu = lds + buf * 65536 + 32768 + qc * 16384;
        #pragma unroll
        for (int q = 0; q < 2; ++q) {
            const int o  = w * 2048 + q * 1024;
            const int kh = o >> 13;
            const int ci = ((o & 8191) >> 6) + lq;
            const int col = c_ * 256 + qc * 64 + (ci & 63) + ((ci >> 6) << 7);
            const f16* src = B + (size_t)col * DIM + koff + kh * 32 + gsw * 8;
            gload_lds16(src, dstu + o);
        }
    };
    auto readA = [&](int kh, int buf) {
        const char* ab = lds + buf * 65536 + kh * 16384;
        #pragma unroll
        for (int i = 0; i < 4; ++i)
            a[i] = *(const f16x8*)(ab + (wm * 64 + i * 16 + l15) * 64 + slot16);
    };
    auto readB = [&](int kh, int qc, int buf) {
        const char* bb = lds + buf * 65536 + 32768 + qc * 16384 + kh * 8192;
        #pragma unroll
        for (int j = 0; j < 4; ++j)
            bfr[j] = *(const f16x8*)(bb + (wn * 64 + j * 16 + l15) * 64 + slot16);
    };
    auto mf0 = [&]() {
        #pragma unroll
        for (int i = 0; i < 4; ++i)
            #pragma unroll
            for (int jj = 0; jj < 4; ++jj)
                acc[i][jj] = MFMA16(a[i], bfr[jj], acc[i][jj]);
    };
    auto mf1 = [&]() {
        #pragma unroll
        for (int i = 0; i < 4; ++i)
            #pragma unroll
            for (int jj = 0; jj < 4; ++jj)
                acc[i][4 + jj] = MFMA16(a[i], bfr[jj], acc[i][4 + jj]);
    };

    // ---- prologue: e2 stash + 6 staged units, then vmcnt(8)+barrier
    ((f32x4*)e2s)[tid] = ((const f32x4*)e2)[tid];
    stageA(0, 0, 0);        // A0 tile0
    stageB(0, 0, 0, 0);     // Bs0 tile0
    stageA(1, 0, 0);        // A1 tile0
    stageA(0, 1, 1);        // A0 tile1
    stageB(1, 0, 0, 0);     // Bs1 tile0
    stageB(0, 0, 1, 1);     // Bs0 tile1
    asm volatile("s_waitcnt vmcnt(8)" ::: "memory");
    __builtin_amdgcn_s_barrier();

    int c = 0, s = 0;
    for (int t = 0; t < TT; ++t) {
        const int buf = t & 1, bo = buf ^ 1;
        int s1 = s + 1, c1 = c; if (s1 == 12) { s1 = 0; ++c1; }
        int s2 = s1 + 1, c2 = c1; if (s2 == 12) { s2 = 0; ++c2; }
        const bool st1 = (c1 < 8), st2 = (c2 < 8);

        if (s == 0) {
            #pragma unroll
            for (int i = 0; i < 4; ++i)
                #pragma unroll
                for (int j = 0; j < 8; ++j)
                    acc[i][j] = (f32x4){0.f, 0.f, 0.f, 0.f};
        }

        // ---- phase 0: (kh0, qc0); stage A1(t+1)
        readA(0, buf); readB(0, 0, buf);
        if (st1) stageA(1, s1, bo);
        asm volatile("s_waitcnt vmcnt(4)" ::: "memory");
        __builtin_amdgcn_s_barrier();
        asm volatile("s_waitcnt lgkmcnt(0)" ::: "memory");
        __builtin_amdgcn_sched_barrier(0);
        __builtin_amdgcn_s_setprio(1);
        mf0();
        __builtin_amdgcn_s_setprio(0);
        __builtin_amdgcn_sched_barrier(0);
        __builtin_amdgcn_s_barrier();

        // ---- phase 1: (kh0, qc1); stage A0(t+2)
        readB(0, 1, buf);
        if (st2) stageA(0, s2, buf);
        __builtin_amdgcn_s_barrier();
        asm volatile("s_waitcnt lgkmcnt(0)" ::: "memory");
        __builtin_amdgcn_sched_barrier(0);
        __builtin_amdgcn_s_setprio(1);
        mf1();
        __builtin_amdgcn_s_setprio(0);
        __builtin_amdgcn_sched_barrier(0);
        __builtin_amdgcn_s_barrier();

        // ---- phase 2: (kh1, qc0); stage Bs1(t+1)
        readA(1, buf); readB(1, 0, buf);
        if (st1) stageB(1, c1, s1, bo);
        __builtin_amdgcn_s_barrier();
        asm volatile("s_waitcnt lgkmcnt(0)" ::: "memory");
        __builtin_amdgcn_sched_barrier(0);
        __builtin_amdgcn_s_setprio(1);
        mf0();
        __builtin_amdgcn_s_setprio(0);
        __builtin_amdgcn_sched_barrier(0);
        __builtin_amdgcn_s_barrier();

        // ---- phase 3: (kh1, qc1); stage Bs0(t+2); counted vmcnt
        readB(1, 1, buf);
        if (st2) stageB(0, c2, s2, buf);
        if (t >= TT - 2) asm volatile("s_waitcnt vmcnt(0)" ::: "memory");
        else             asm volatile("s_waitcnt vmcnt(8)" ::: "memory");
        __builtin_amdgcn_s_barrier();
        asm volatile("s_waitcnt lgkmcnt(0)" ::: "memory");
        __builtin_amdgcn_sched_barrier(0);
        __builtin_amdgcn_s_setprio(1);
        mf1();
        __builtin_amdgcn_s_setprio(0);
        __builtin_amdgcn_sched_barrier(0);
        __builtin_amdgcn_s_barrier();

        // ---- fold argmin at end of each code-tile
        if (s == 11) {
            const int cbase = c * 256 + wn * 128;
            #pragma unroll
            for (int j = 0; j < 8; ++j) {
                const int col = cbase + j * 16 + l15;
                const float e2v = e2s[col];
                #pragma unroll
                for (int i = 0; i < 4; ++i)
                    #pragma unroll
                    for (int r = 0; r < 4; ++r) {
                        float m = fmaf(-2.0f, acc[i][j][r], e2v);
                        const int tt_ = i * 4 + r;
                        if (m < best[tt_]) { best[tt_] = m; bidx[tt_] = col; }
                    }
            }
        }
        if (++s == 12) { s = 0; ++c; }
    }

    // ---- final reduce: 16 col-lanes, then 2 col-waves via LDS
    __syncthreads();
    float* rv = (float*)lds;
    int*   ri = (int*)(lds + 4096);
    #pragma unroll
    for (int tt_ = 0; tt_ < 16; ++tt_) {
        float v = best[tt_];
        int  ix = bidx[tt_];
        #pragma unroll
        for (int m = 1; m <= 8; m <<= 1) {
            float ov = __shfl_xor(v, m, 64);
            int  oix = __shfl_xor(ix, m, 64);
            if (ov < v || (ov == v && oix < ix)) { v = ov; ix = oix; }
        }
        if (l15 == 0) {
            const int rl = wm * 64 + (tt_ >> 2) * 16 + l4 * 4 + (tt_ & 3);
            rv[rl * 2 + wn] = v;
            ri[rl * 2 + wn] = ix;
        }
    }
    __syncthreads();
    if (tid < 256) {
        float v0 = rv[tid * 2], v1 = rv[tid * 2 + 1];
        int   i0 = ri[tid * 2], i1 = ri[tid * 2 + 1];
        int ib = (v1 < v0 || (v1 == v0 && i1 < i0)) ? i1 : i0;
        flat_ind[row0 + tid] = ib;
        atomicAdd(&cnt[ib], 1);
    }
}

// ---------------------------------------------------------------------------
// scan: exclusive prefix sum over 2048 counts -> offsets, cursor
// ---------------------------------------------------------------------------
__global__ __launch_bounds__(256) void scan_kernel(
    const int* __restrict__ cnt, int* __restrict__ offs, int* __restrict__ cursor)
{
    __shared__ int ps[256];
    const int t = threadIdx.x;
    int pre[8], s = 0;
    #pragma unroll
    for (int j = 0; j < 8; ++j) { pre[j] = s; s += cnt[t * 8 + j]; }
    ps[t] = s;
    __syncthreads();
    for (int off = 1; off < 256; off <<= 1) {
        int v = (t >= off) ? ps[t - off] : 0;
        __syncthreads();
        ps[t] += v;
        __syncthreads();
    }
    int ex = (t > 0) ? ps[t - 1] : 0;
    #pragma unroll
    for (int j = 0; j < 8; ++j) {
        offs[t * 8 + j]   = ex + pre[j];
        cursor[t * 8 + j] = ex + pre[j];
    }
}

// ---------------------------------------------------------------------------
// assign: rowlist[cursor[ind]++] = row   (counting-sort placement)
// ---------------------------------------------------------------------------
__global__ __launch_bounds__(256) void assign_kernel(
    const int* __restrict__ flat_ind, int* __restrict__ cursor,
    int* __restrict__ rowlist, int N)
{
    int i = blockIdx.x * 256 + threadIdx.x;
    if (i < N) {
        int pos = atomicAdd(&cursor[flat_ind[i]], 1);
        rowlist[pos] = i;
    }
}

// ---------------------------------------------------------------------------
// codesum: per-code row-sum (no fp atomics) + fused EMA finalize
// ---------------------------------------------------------------------------
__global__ __launch_bounds__(256) void codesum_kernel(
    const float* __restrict__ x, const int* __restrict__ rowlist,
    const int* __restrict__ offs, const int* __restrict__ cnt,
    const float* __restrict__ embed_sum, const float* __restrict__ usage,
    float* __restrict__ out_usage, float* __restrict__ out_es)
{
    const int k = blockIdx.x, d = threadIdx.x;
    const int start = offs[k], n = cnt[k];
    float acc = 0.f;
    for (int r = 0; r < n; ++r)
        acc += x[(size_t)rowlist[start + r] * DIM + d];
    out_es[k * DIM + d] = embed_sum[k * DIM + d] * DECAYF + acc * (1.0f - DECAYF);
    if (d == 0)
        out_usage[k] = usage[k] * DECAYF + (float)n * (1.0f - DECAYF);
}

// ---------------------------------------------------------------------------
// quantize: out_q = embed[flat_ind], out_ind = (float)flat_ind
// ---------------------------------------------------------------------------
__global__ __launch_bounds__(256) void quantize_kernel(
    const float* __restrict__ embed, const int* __restrict__ flat_ind,
    float* __restrict__ out_q, float* __restrict__ out_ind_f, int N)
{
    int i = blockIdx.x * 256 + threadIdx.x;   // over N*64 float4s
    int row = i >> 6, c4 = i & 63;
    int ind = flat_ind[row];
    ((f32x4*)out_q)[i] = ((const f32x4*)embed)[ind * 64 + c4];
    if (i < N) out_ind_f[i] = (float)flat_ind[i];
}

extern "C" void kernel_launch(void* const* d_in, const int* in_sizes, int n_in,
                              void* d_out, int out_size, void* d_ws, size_t ws_size,
                              hipStream_t stream)
{
    const float* hs        = (const float*)d_in[0];
    const float* embed_sum = (const float*)d_in[1];
    const float* usage     = (const float*)d_in[2];
    const int N = in_sizes[0] / DIM;   // 65536

    float* ws_f    = (float*)d_ws;
    float* embed   = ws_f;                        // K*D f32 (2MB)
    float* e2      = embed + KCODES * DIM;        // K
    f16*   eh      = (f16*)(e2 + KCODES);         // K*D f16
    f16*   el      = eh + KCODES * DIM;           // K*D f16
    int*   cnt     = (int*)(el + KCODES * DIM);   // K
    int*   offs    = cnt + KCODES;                // K
    int*   cursor  = offs + KCODES;               // K
    int*   rowlist = cursor + KCODES;             // N
    int*   flat_ind= rowlist + N;                 // N

    float* out_q     = (float*)d_out;             // N*D
    float* out_ind   = out_q + (size_t)N * DIM;   // N
    float* out_usage = out_ind + N;               // K
    float* out_es    = out_usage + KCODES;        // K*D

    // xh/xl live in the out_q region (exactly N*D*4B); quantize overwrites later
    f16* xh = (f16*)out_q;
    f16* xl = xh + (size_t)N * DIM;

    hipMemsetAsync(cnt, 0, KCODES * sizeof(int), stream);

    split_x_kernel<<<(N * DIM / 8 + 255) / 256, 256, 0, stream>>>(hs, xh, xl, N * DIM / 8);
    prep_embed_kernel<<<KCODES, 256, 0, stream>>>(embed_sum, usage, embed, eh, el, e2);
    argmin_kernel<<<N / 256, 512, 0, stream>>>(xh, xl, eh, el, e2, flat_ind, cnt);
    scan_kernel<<<1, 256, 0, stream>>>(cnt, offs, cursor);
    assign_kernel<<<(N + 255) / 256, 256, 0, stream>>>(flat_ind, cursor, rowlist, N);
    codesum_kernel<<<KCODES, 256, 0, stream>>>(hs, rowlist, offs, cnt, embed_sum, usage,
                                               out_usage, out_es);
    quantize_kernel<<<N * DIM / 4 / 256, 256, 0, stream>>>(embed, flat_ind, out_q, out_ind, N);
}

// Round 5
// 334.073 us; speedup vs baseline: 5.0108x; 5.0108x over previous
//
#include <hip/hip_runtime.h>

#define EPSF 1e-5f
#define DECAYF 0.99f
#define KCODES 2048
#define DIM 256
#define TT 96          // 8 code-tiles x 12 virtual K-tiles (K=768 / 64)

typedef _Float16 f16;
typedef f16 f16x8 __attribute__((ext_vector_type(8)));
typedef float f32x4 __attribute__((ext_vector_type(4)));

#define MFMA16(A, B, C) __builtin_amdgcn_mfma_f32_16x16x32_f16(A, B, C, 0, 0, 0)

__device__ __forceinline__ void gload_lds16(const void* g, void* l) {
    __builtin_amdgcn_global_load_lds(
        (const __attribute__((address_space(1))) void*)g,
        (__attribute__((address_space(3))) void*)l, 16, 0, 0);
}

// ---------------------------------------------------------------------------
// split_x: xh = (f16)x, xl = (f16)(x - xh)
// ---------------------------------------------------------------------------
__global__ __launch_bounds__(256) void split_x_kernel(
    const float* __restrict__ x, f16* __restrict__ xh, f16* __restrict__ xl, int n8)
{
    int i = blockIdx.x * 256 + threadIdx.x;
    if (i >= n8) return;
    f32x4 v0 = ((const f32x4*)x)[2 * i];
    f32x4 v1 = ((const f32x4*)x)[2 * i + 1];
    f16x8 h, l;
    #pragma unroll
    for (int t = 0; t < 4; ++t) {
        f16 h0 = (f16)v0[t]; h[t] = h0; l[t] = (f16)(v0[t] - (float)h0);
        f16 h1 = (f16)v1[t]; h[t + 4] = h1; l[t + 4] = (f16)(v1[t] - (float)h1);
    }
    ((f16x8*)xh)[i] = h;
    ((f16x8*)xl)[i] = l;
}

// ---------------------------------------------------------------------------
// prep: embed = embed_sum / clamp(usage); e2 = ||embed||^2; eh/el f16 split
// ---------------------------------------------------------------------------
__global__ __launch_bounds__(256) void prep_embed_kernel(
    const float* __restrict__ embed_sum, const float* __restrict__ usage,
    float* __restrict__ embed, f16* __restrict__ eh, f16* __restrict__ el,
    float* __restrict__ e2)
{
    int k = blockIdx.x;
    int d = threadIdx.x;
    float inv = 1.0f / fmaxf(usage[k], EPSF);
    float e = embed_sum[k * DIM + d] * inv;
    embed[k * DIM + d] = e;
    float ec = fminf(fmaxf(e, -65000.0f), 65000.0f);
    f16 h = (f16)ec;
    f16 l = (f16)(ec - (float)h);
    eh[k * DIM + d] = h;
    el[k * DIM + d] = l;
    float sq = e * e;
    #pragma unroll
    for (int off = 32; off > 0; off >>= 1) sq += __shfl_down(sq, off, 64);
    __shared__ float ws[4];
    if ((threadIdx.x & 63) == 0) ws[threadIdx.x >> 6] = sq;
    __syncthreads();
    if (threadIdx.x == 0) e2[k] = ws[0] + ws[1] + ws[2] + ws[3];
}

// ---------------------------------------------------------------------------
// argmin: 8-phase-style pipelined f16 GEMM-argmin (unchanged from round 4,
// except the histogram atomic is now wave-aggregated).
// ---------------------------------------------------------------------------
__global__ __launch_bounds__(512, 2) void argmin_kernel(
    const f16* __restrict__ xh, const f16* __restrict__ xl,
    const f16* __restrict__ eh, const f16* __restrict__ el,
    const float* __restrict__ e2, int* __restrict__ flat_ind, int* __restrict__ cnt)
{
    __shared__ __align__(1024) char lds[2 * 65536 + 8192];
    float* e2s = (float*)(lds + 131072);

    const int tid  = threadIdx.x;
    const int w    = tid >> 6, lane = tid & 63;
    const int l15  = lane & 15, l4 = lane >> 4;
    const int wm   = w >> 1, wn = w & 1;
    const int row0 = blockIdx.x * 256;
    const int gsw  = (lane & 3) ^ ((lane >> 2) & 3);
    const int lq   = lane >> 2;
    const int slot16 = (l4 ^ (l15 & 3)) * 16;

    f32x4 acc[4][8];
    f16x8 a[4], bfr[4];
    float best[16];
    int   bidx[16];
    #pragma unroll
    for (int t = 0; t < 16; ++t) { best[t] = 3.4e38f; bidx[t] = 0; }

    auto segA = [&](int s_) { return (s_ < 8) ? xh : xl; };
    auto segB = [&](int s_) { return (s_ >= 4 && s_ < 8) ? el : eh; };

    auto stageA = [&](int kh, int s_, int buf) {
        const f16* A = segA(s_);
        const int koff = (s_ & 3) * 64 + kh * 32;
        char* dst = lds + buf * 65536 + kh * 16384 + w * 2048;
        #pragma unroll
        for (int q = 0; q < 2; ++q) {
            const int row = w * 32 + q * 16 + lq;
            const f16* src = A + (size_t)(row0 + row) * DIM + koff + gsw * 8;
            gload_lds16(src, dst + q * 1024);
        }
    };
    auto stageB = [&](int qc, int c_, int s_, int buf) {
        const f16* B = segB(s_);
        const int koff = (s_ & 3) * 64;
        char* dstu = lds + buf * 65536 + 32768 + qc * 16384;
        #pragma unroll
        for (int q = 0; q < 2; ++q) {
            const int o  = w * 2048 + q * 1024;
            const int kh = o >> 13;
            const int ci = ((o & 8191) >> 6) + lq;
            const int col = c_ * 256 + qc * 64 + (ci & 63) + ((ci >> 6) << 7);
            const f16* src = B + (size_t)col * DIM + koff + kh * 32 + gsw * 8;
            gload_lds16(src, dstu + o);
        }
    };
    auto readA = [&](int kh, int buf) {
        const char* ab = lds + buf * 65536 + kh * 16384;
        #pragma unroll
        for (int i = 0; i < 4; ++i)
            a[i] = *(const f16x8*)(ab + (wm * 64 + i * 16 + l15) * 64 + slot16);
    };
    auto readB = [&](int kh, int qc, int buf) {
        const char* bb = lds + buf * 65536 + 32768 + qc * 16384 + kh * 8192;
        #pragma unroll
        for (int j = 0; j < 4; ++j)
            bfr[j] = *(const f16x8*)(bb + (wn * 64 + j * 16 + l15) * 64 + slot16);
    };
    auto mf0 = [&]() {
        #pragma unroll
        for (int i = 0; i < 4; ++i)
            #pragma unroll
            for (int jj = 0; jj < 4; ++jj)
                acc[i][jj] = MFMA16(a[i], bfr[jj], acc[i][jj]);
    };
    auto mf1 = [&]() {
        #pragma unroll
        for (int i = 0; i < 4; ++i)
            #pragma unroll
            for (int jj = 0; jj < 4; ++jj)
                acc[i][4 + jj] = MFMA16(a[i], bfr[jj], acc[i][4 + jj]);
    };

    ((f32x4*)e2s)[tid] = ((const f32x4*)e2)[tid];
    stageA(0, 0, 0);
    stageB(0, 0, 0, 0);
    stageA(1, 0, 0);
    stageA(0, 1, 1);
    stageB(1, 0, 0, 0);
    stageB(0, 0, 1, 1);
    asm volatile("s_waitcnt vmcnt(8)" ::: "memory");
    __builtin_amdgcn_s_barrier();

    int c = 0, s = 0;
    for (int t = 0; t < TT; ++t) {
        const int buf = t & 1, bo = buf ^ 1;
        int s1 = s + 1, c1 = c; if (s1 == 12) { s1 = 0; ++c1; }
        int s2 = s1 + 1, c2 = c1; if (s2 == 12) { s2 = 0; ++c2; }
        const bool st1 = (c1 < 8), st2 = (c2 < 8);

        if (s == 0) {
            #pragma unroll
            for (int i = 0; i < 4; ++i)
                #pragma unroll
                for (int j = 0; j < 8; ++j)
                    acc[i][j] = (f32x4){0.f, 0.f, 0.f, 0.f};
        }

        // phase 0
        readA(0, buf); readB(0, 0, buf);
        if (st1) stageA(1, s1, bo);
        asm volatile("s_waitcnt vmcnt(4)" ::: "memory");
        __builtin_amdgcn_s_barrier();
        asm volatile("s_waitcnt lgkmcnt(0)" ::: "memory");
        __builtin_amdgcn_sched_barrier(0);
        __builtin_amdgcn_s_setprio(1);
        mf0();
        __builtin_amdgcn_s_setprio(0);
        __builtin_amdgcn_sched_barrier(0);
        __builtin_amdgcn_s_barrier();

        // phase 1
        readB(0, 1, buf);
        if (st2) stageA(0, s2, buf);
        __builtin_amdgcn_s_barrier();
        asm volatile("s_waitcnt lgkmcnt(0)" ::: "memory");
        __builtin_amdgcn_sched_barrier(0);
        __builtin_amdgcn_s_setprio(1);
        mf1();
        __builtin_amdgcn_s_setprio(0);
        __builtin_amdgcn_sched_barrier(0);
        __builtin_amdgcn_s_barrier();

        // phase 2
        readA(1, buf); readB(1, 0, buf);
        if (st1) stageB(1, c1, s1, bo);
        __builtin_amdgcn_s_barrier();
        asm volatile("s_waitcnt lgkmcnt(0)" ::: "memory");
        __builtin_amdgcn_sched_barrier(0);
        __builtin_amdgcn_s_setprio(1);
        mf0();
        __builtin_amdgcn_s_setprio(0);
        __builtin_amdgcn_sched_barrier(0);
        __builtin_amdgcn_s_barrier();

        // phase 3
        readB(1, 1, buf);
        if (st2) stageB(0, c2, s2, buf);
        if (t >= TT - 2) asm volatile("s_waitcnt vmcnt(0)" ::: "memory");
        else             asm volatile("s_waitcnt vmcnt(8)" ::: "memory");
        __builtin_amdgcn_s_barrier();
        asm volatile("s_waitcnt lgkmcnt(0)" ::: "memory");
        __builtin_amdgcn_sched_barrier(0);
        __builtin_amdgcn_s_setprio(1);
        mf1();
        __builtin_amdgcn_s_setprio(0);
        __builtin_amdgcn_sched_barrier(0);
        __builtin_amdgcn_s_barrier();

        if (s == 11) {
            const int cbase = c * 256 + wn * 128;
            #pragma unroll
            for (int j = 0; j < 8; ++j) {
                const int col = cbase + j * 16 + l15;
                const float e2v = e2s[col];
                #pragma unroll
                for (int i = 0; i < 4; ++i)
                    #pragma unroll
                    for (int r = 0; r < 4; ++r) {
                        float m = fmaf(-2.0f, acc[i][j][r], e2v);
                        const int tt_ = i * 4 + r;
                        if (m < best[tt_]) { best[tt_] = m; bidx[tt_] = col; }
                    }
            }
        }
        if (++s == 12) { s = 0; ++c; }
    }

    // final reduce
    __syncthreads();
    float* rv = (float*)lds;
    int*   ri = (int*)(lds + 4096);
    #pragma unroll
    for (int tt_ = 0; tt_ < 16; ++tt_) {
        float v = best[tt_];
        int  ix = bidx[tt_];
        #pragma unroll
        for (int m = 1; m <= 8; m <<= 1) {
            float ov = __shfl_xor(v, m, 64);
            int  oix = __shfl_xor(ix, m, 64);
            if (ov < v || (ov == v && oix < ix)) { v = ov; ix = oix; }
        }
        if (l15 == 0) {
            const int rl = wm * 64 + (tt_ >> 2) * 16 + l4 * 4 + (tt_ & 3);
            rv[rl * 2 + wn] = v;
            ri[rl * 2 + wn] = ix;
        }
    }
    __syncthreads();
    if (tid < 256) {
        float v0 = rv[tid * 2], v1 = rv[tid * 2 + 1];
        int   i0 = ri[tid * 2], i1 = ri[tid * 2 + 1];
        int ib = (v1 < v0 || (v1 == v0 && i1 < i0)) ? i1 : i0;
        flat_ind[row0 + tid] = ib;
        // wave-aggregated histogram (skew-proof)
        unsigned long long pending = ~0ULL;
        while (pending) {
            int leader = __ffsll((long long)pending) - 1;
            int lind = __shfl(ib, leader, 64);
            unsigned long long same = __ballot(ib == lind);
            if ((tid & 63) == leader) atomicAdd(&cnt[lind], (int)__popcll(same));
            pending &= ~same;
        }
    }
}

// ---------------------------------------------------------------------------
// scan: exclusive prefix sum over 2048 counts -> offsets, cursor
// ---------------------------------------------------------------------------
__global__ __launch_bounds__(256) void scan_kernel(
    const int* __restrict__ cnt, int* __restrict__ offs, int* __restrict__ cursor)
{
    __shared__ int ps[256];
    const int t = threadIdx.x;
    int pre[8], s = 0;
    #pragma unroll
    for (int j = 0; j < 8; ++j) { pre[j] = s; s += cnt[t * 8 + j]; }
    ps[t] = s;
    __syncthreads();
    for (int off = 1; off < 256; off <<= 1) {
        int v = (t >= off) ? ps[t - off] : 0;
        __syncthreads();
        ps[t] += v;
        __syncthreads();
    }
    int ex = (t > 0) ? ps[t - 1] : 0;
    #pragma unroll
    for (int j = 0; j < 8; ++j) {
        offs[t * 8 + j]   = ex + pre[j];
        cursor[t * 8 + j] = ex + pre[j];
    }
}

// ---------------------------------------------------------------------------
// assign: counting-sort placement with wave-aggregated cursor atomics.
// Writes rowlist[pos] = row and codesorted[pos] = code.
// ---------------------------------------------------------------------------
__global__ __launch_bounds__(256) void assign_kernel(
    const int* __restrict__ flat_ind, int* __restrict__ cursor,
    int* __restrict__ rowlist, int* __restrict__ codesorted)
{
    const int i    = blockIdx.x * 256 + threadIdx.x;
    const int lane = threadIdx.x & 63;
    const int ind  = flat_ind[i];
    int pos = 0;
    unsigned long long pending = ~0ULL;
    while (pending) {
        int leader = __ffsll((long long)pending) - 1;
        int lind = __shfl(ind, leader, 64);
        unsigned long long same = __ballot(ind == lind);
        if (ind == lind) {
            int base = 0;
            if (lane == leader) base = atomicAdd(&cursor[lind], (int)__popcll(same));
            base = __shfl(base, leader, 64);
            pos = base + (int)__popcll(same & ((1ULL << lane) - 1ULL));
        }
        pending &= ~same;
    }
    rowlist[pos] = i;
    codesorted[pos] = ind;
}

// ---------------------------------------------------------------------------
// codesum: chunked segmented reduction over the sorted rowlist.
// Each block reduces 64 sorted rows (thread = one d); atomic flush only at
// code boundaries. Balanced regardless of code-count skew.
// ---------------------------------------------------------------------------
__global__ __launch_bounds__(256) void codesum_kernel(
    const float* __restrict__ x, const int* __restrict__ rowlist,
    const int* __restrict__ codesorted, float* __restrict__ sums)
{
    const int p0 = blockIdx.x * 64;
    __shared__ int rows[64], codes[64];
    if (threadIdx.x < 64) {
        rows[threadIdx.x]  = rowlist[p0 + threadIdx.x];
        codes[threadIdx.x] = codesorted[p0 + threadIdx.x];
    }
    __syncthreads();
    const int d = threadIdx.x;
    float acc = 0.f;
    int cur = codes[0];
    #pragma unroll 4
    for (int r = 0; r < 64; ++r) {
        const int c = codes[r];
        if (c != cur) {
            atomicAdd(&sums[(size_t)cur * DIM + d], acc);
            acc = 0.f; cur = c;
        }
        acc += x[(size_t)rows[r] * DIM + d];
    }
    atomicAdd(&sums[(size_t)cur * DIM + d], acc);
}

// ---------------------------------------------------------------------------
// finalize: EMA update outputs
// ---------------------------------------------------------------------------
__global__ __launch_bounds__(256) void finalize_kernel(
    const float* __restrict__ embed_sum, const float* __restrict__ usage,
    const float* __restrict__ sums, const int* __restrict__ cnt,
    float* __restrict__ out_usage, float* __restrict__ out_es)
{
    const int k = blockIdx.x, d = threadIdx.x;
    out_es[k * DIM + d] = embed_sum[k * DIM + d] * DECAYF + sums[k * DIM + d] * (1.0f - DECAYF);
    if (d == 0)
        out_usage[k] = usage[k] * DECAYF + (float)cnt[k] * (1.0f - DECAYF);
}

// ---------------------------------------------------------------------------
// quantize: out_q = embed[flat_ind], out_ind = (float)flat_ind
// ---------------------------------------------------------------------------
__global__ __launch_bounds__(256) void quantize_kernel(
    const float* __restrict__ embed, const int* __restrict__ flat_ind,
    float* __restrict__ out_q, float* __restrict__ out_ind_f, int N)
{
    int i = blockIdx.x * 256 + threadIdx.x;   // over N*64 float4s
    int row = i >> 6, c4 = i & 63;
    int ind = flat_ind[row];
    ((f32x4*)out_q)[i] = ((const f32x4*)embed)[ind * 64 + c4];
    if (i < N) out_ind_f[i] = (float)flat_ind[i];
}

extern "C" void kernel_launch(void* const* d_in, const int* in_sizes, int n_in,
                              void* d_out, int out_size, void* d_ws, size_t ws_size,
                              hipStream_t stream)
{
    const float* hs        = (const float*)d_in[0];
    const float* embed_sum = (const float*)d_in[1];
    const float* usage     = (const float*)d_in[2];
    const int N = in_sizes[0] / DIM;   // 65536

    float* ws_f      = (float*)d_ws;
    float* embed     = ws_f;                         // K*D f32
    float* e2        = embed + KCODES * DIM;         // K
    float* sums      = e2 + KCODES;                  // K*D f32
    f16*   eh        = (f16*)(sums + KCODES * DIM);  // K*D f16
    f16*   el        = eh + KCODES * DIM;            // K*D f16
    int*   cnt       = (int*)(el + KCODES * DIM);    // K
    int*   offs      = cnt + KCODES;                 // K
    int*   cursor    = offs + KCODES;                // K
    int*   rowlist   = cursor + KCODES;              // N
    int*   codesorted= rowlist + N;                  // N
    int*   flat_ind  = codesorted + N;               // N

    float* out_q     = (float*)d_out;                // N*D
    float* out_ind   = out_q + (size_t)N * DIM;      // N
    float* out_usage = out_ind + N;                  // K
    float* out_es    = out_usage + KCODES;           // K*D

    // xh/xl live in the out_q region (exactly N*D*4B); quantize overwrites later
    f16* xh = (f16*)out_q;
    f16* xl = xh + (size_t)N * DIM;

    hipMemsetAsync(cnt, 0, KCODES * sizeof(int), stream);
    hipMemsetAsync(sums, 0, (size_t)KCODES * DIM * sizeof(float), stream);

    split_x_kernel<<<(N * DIM / 8 + 255) / 256, 256, 0, stream>>>(hs, xh, xl, N * DIM / 8);
    prep_embed_kernel<<<KCODES, 256, 0, stream>>>(embed_sum, usage, embed, eh, el, e2);
    argmin_kernel<<<N / 256, 512, 0, stream>>>(xh, xl, eh, el, e2, flat_ind, cnt);
    scan_kernel<<<1, 256, 0, stream>>>(cnt, offs, cursor);
    assign_kernel<<<N / 256, 256, 0, stream>>>(flat_ind, cursor, rowlist, codesorted);
    codesum_kernel<<<N / 64, 256, 0, stream>>>(hs, rowlist, codesorted, sums);
    finalize_kernel<<<KCODES, 256, 0, stream>>>(embed_sum, usage, sums, cnt, out_usage, out_es);
    quantize_kernel<<<N * DIM / 4 / 256, 256, 0, stream>>>(embed, flat_ind, out_q, out_ind, N);
}

// Round 6
// 300.687 us; speedup vs baseline: 5.5672x; 1.1110x over previous
//
#include <hip/hip_runtime.h>

#define EPSF 1e-5f
#define DECAYF 0.99f
#define KCODES 2048
#define DIM 256
#define CC 64          // 8 code-tiles x 8 d-chunks of 32

typedef _Float16 f16;
typedef f16 f16x8 __attribute__((ext_vector_type(8)));
typedef float f32x4 __attribute__((ext_vector_type(4)));

#define MFMA16(A, B, C) __builtin_amdgcn_mfma_f32_16x16x32_f16(A, B, C, 0, 0, 0)

#define OFF_AH 0
#define OFF_AL 16384
#define OFF_BH 32768
#define OFF_BL 49152

__device__ __forceinline__ void gload_lds16(const void* g, void* l) {
    __builtin_amdgcn_global_load_lds(
        (const __attribute__((address_space(1))) void*)g,
        (__attribute__((address_space(3))) void*)l, 16, 0, 0);
}

// ---------------------------------------------------------------------------
// split_x: xh = (f16)x, xl = (f16)(x - xh)
// ---------------------------------------------------------------------------
__global__ __launch_bounds__(256) void split_x_kernel(
    const float* __restrict__ x, f16* __restrict__ xh, f16* __restrict__ xl, int n8)
{
    int i = blockIdx.x * 256 + threadIdx.x;
    if (i >= n8) return;
    f32x4 v0 = ((const f32x4*)x)[2 * i];
    f32x4 v1 = ((const f32x4*)x)[2 * i + 1];
    f16x8 h, l;
    #pragma unroll
    for (int t = 0; t < 4; ++t) {
        f16 h0 = (f16)v0[t]; h[t] = h0; l[t] = (f16)(v0[t] - (float)h0);
        f16 h1 = (f16)v1[t]; h[t + 4] = h1; l[t + 4] = (f16)(v1[t] - (float)h1);
    }
    ((f16x8*)xh)[i] = h;
    ((f16x8*)xl)[i] = l;
}

// ---------------------------------------------------------------------------
// prep: embed = embed_sum / clamp(usage); e2 = ||embed||^2; eh/el f16 split
// ---------------------------------------------------------------------------
__global__ __launch_bounds__(256) void prep_embed_kernel(
    const float* __restrict__ embed_sum, const float* __restrict__ usage,
    float* __restrict__ embed, f16* __restrict__ eh, f16* __restrict__ el,
    float* __restrict__ e2)
{
    int k = blockIdx.x;
    int d = threadIdx.x;
    float inv = 1.0f / fmaxf(usage[k], EPSF);
    float e = embed_sum[k * DIM + d] * inv;
    embed[k * DIM + d] = e;
    float ec = fminf(fmaxf(e, -65000.0f), 65000.0f);
    f16 h = (f16)ec;
    f16 l = (f16)(ec - (float)h);
    eh[k * DIM + d] = h;
    el[k * DIM + d] = l;
    float sq = e * e;
    #pragma unroll
    for (int off = 32; off > 0; off >>= 1) sq += __shfl_down(sq, off, 64);
    __shared__ float ws[4];
    if ((threadIdx.x & 63) == 0) ws[threadIdx.x >> 6] = sq;
    __syncthreads();
    if (threadIdx.x == 0) e2[k] = ws[0] + ws[1] + ws[2] + ws[3];
}

// ---------------------------------------------------------------------------
// argmin: fragment-shared 3-phase pipelined f16 GEMM-argmin.
// BM=256 x BN=256, 8 waves (4M x 2N, wave tile 64x128), 16x16x32 f16.
// Per 32-d chunk: stage {Ah,Al,Bh,Bl} once (4 x 16KB units); 3 phases:
// Ah*Bh, Ah*Bl (A regs held), Al*Bh. Chunk-parity double buffer (stages
// always target the other buffer), counted vmcnt(8), corrected XOR swizzle
// (granule ^= (row>>1)&3) -> conflict-free ds_read_b128.
// ---------------------------------------------------------------------------
__global__ __launch_bounds__(512, 2) void argmin_kernel(
    const f16* __restrict__ xh, const f16* __restrict__ xl,
    const f16* __restrict__ eh, const f16* __restrict__ el,
    const float* __restrict__ e2, int* __restrict__ flat_ind, int* __restrict__ cnt)
{
    __shared__ __align__(1024) char lds[2 * 65536 + 8192];
    float* e2s = (float*)(lds + 131072);

    const int tid  = threadIdx.x;
    const int w    = tid >> 6, lane = tid & 63;
    const int l15  = lane & 15, l4 = lane >> 4;
    const int wm   = w >> 1, wn = w & 1;
    const int row0 = blockIdx.x * 256;
    const int gsw  = (lane & 3) ^ ((lane >> 3) & 3);     // write-side inverse swizzle
    const int lq   = lane >> 2;
    const int rslot = (l4 ^ ((l15 >> 1) & 3)) * 16;      // read-side swizzled slot

    f32x4 acc[4][8];
    f16x8 a[4], b[8];
    float best[16];
    int   bidx[16];
    #pragma unroll
    for (int t = 0; t < 16; ++t) { best[t] = 3.4e38f; bidx[t] = 0; }

    auto stageU = [&](const f16* rowbase, int koff, char* unit) {
        #pragma unroll
        for (int q = 0; q < 2; ++q) {
            const int r = w * 32 + q * 16 + lq;
            gload_lds16(rowbase + (size_t)r * DIM + koff + gsw * 8,
                        unit + w * 2048 + q * 1024 + lane * 16);
        }
    };
    auto readA = [&](const char* unit) {
        #pragma unroll
        for (int i = 0; i < 4; ++i)
            a[i] = *(const f16x8*)(unit + (wm * 64 + i * 16 + l15) * 64 + rslot);
    };
    auto readB = [&](const char* unit) {
        #pragma unroll
        for (int j = 0; j < 8; ++j)
            b[j] = *(const f16x8*)(unit + (wn * 128 + j * 16 + l15) * 64 + rslot);
    };
    auto mf = [&]() {
        #pragma unroll
        for (int i = 0; i < 4; ++i)
            #pragma unroll
            for (int j = 0; j < 8; ++j)
                acc[i][j] = MFMA16(a[i], b[j], acc[i][j]);
    };

    // ---- prologue: e2 stash (drained), then chunk 0 units in FIFO order
    ((f32x4*)e2s)[tid] = ((const f32x4*)e2)[tid];
    asm volatile("s_waitcnt vmcnt(0)" ::: "memory");
    stageU(xh + (size_t)row0 * DIM, 0, lds + OFF_AH);   // Ah0
    stageU(eh, 0, lds + OFF_BH);                        // Bh0
    stageU(el, 0, lds + OFF_BL);                        // Bl0
    stageU(xl + (size_t)row0 * DIM, 0, lds + OFF_AL);   // Al0

    for (int cc = 0; cc < CC; ++cc) {
        char* buf  = lds + (cc & 1) * 65536;
        char* nbuf = lds + ((cc + 1) & 1) * 65536;
        const int ct = cc >> 3, sd = cc & 7;
        const int nct = (cc + 1) >> 3, nsd = (cc + 1) & 7;
        const bool more = (cc + 1 < CC);

        if (sd == 0) {
            #pragma unroll
            for (int i = 0; i < 4; ++i)
                #pragma unroll
                for (int j = 0; j < 8; ++j)
                    acc[i][j] = (f32x4){0.f, 0.f, 0.f, 0.f};
        }

        // ---- phase 0: Ah*Bh ; stage Ah,Bh(next)
        if (more) {
            stageU(xh + (size_t)row0 * DIM, nsd * 32, nbuf + OFF_AH);
            stageU(eh + (size_t)(nct * 256) * DIM, nsd * 32, nbuf + OFF_BH);
            asm volatile("s_waitcnt vmcnt(8)" ::: "memory");
        } else {
            asm volatile("s_waitcnt vmcnt(4)" ::: "memory");
        }
        __builtin_amdgcn_s_barrier();
        __builtin_amdgcn_sched_barrier(0);
        readA(buf + OFF_AH);
        readB(buf + OFF_BH);
        __builtin_amdgcn_s_setprio(1);
        mf();
        __builtin_amdgcn_s_setprio(0);
        __builtin_amdgcn_s_barrier();

        // ---- phase 1: Ah*Bl (A regs held) ; stage Bl(next)
        if (more) {
            stageU(el + (size_t)(nct * 256) * DIM, nsd * 32, nbuf + OFF_BL);
            asm volatile("s_waitcnt vmcnt(8)" ::: "memory");
        } else {
            asm volatile("s_waitcnt vmcnt(2)" ::: "memory");
        }
        __builtin_amdgcn_s_barrier();
        __builtin_amdgcn_sched_barrier(0);
        readB(buf + OFF_BL);
        __builtin_amdgcn_s_setprio(1);
        mf();
        __builtin_amdgcn_s_setprio(0);
        __builtin_amdgcn_s_barrier();

        // ---- phase 2: Al*Bh ; stage Al(next)
        if (more) {
            stageU(xl + (size_t)row0 * DIM, nsd * 32, nbuf + OFF_AL);
            asm volatile("s_waitcnt vmcnt(8)" ::: "memory");
        } else {
            asm volatile("s_waitcnt vmcnt(0)" ::: "memory");
        }
        __builtin_amdgcn_s_barrier();
        __builtin_amdgcn_sched_barrier(0);
        readA(buf + OFF_AL);
        readB(buf + OFF_BH);
        __builtin_amdgcn_s_setprio(1);
        mf();
        __builtin_amdgcn_s_setprio(0);
        __builtin_amdgcn_s_barrier();

        // ---- fold argmin at end of each code-tile
        if (sd == 7) {
            const int cbase = ct * 256 + wn * 128;
            #pragma unroll
            for (int j = 0; j < 8; ++j) {
                const int col = cbase + j * 16 + l15;
                const float e2v = e2s[col];
                #pragma unroll
                for (int i = 0; i < 4; ++i)
                    #pragma unroll
                    for (int r = 0; r < 4; ++r) {
                        float m = fmaf(-2.0f, acc[i][j][r], e2v);
                        const int tt_ = i * 4 + r;
                        if (m < best[tt_]) { best[tt_] = m; bidx[tt_] = col; }
                    }
            }
        }
    }

    // ---- final reduce: 16 col-lanes, then 2 col-waves via LDS
    __syncthreads();
    float* rv = (float*)lds;
    int*   ri = (int*)(lds + 4096);
    #pragma unroll
    for (int tt_ = 0; tt_ < 16; ++tt_) {
        float v = best[tt_];
        int  ix = bidx[tt_];
        #pragma unroll
        for (int m = 1; m <= 8; m <<= 1) {
            float ov = __shfl_xor(v, m, 64);
            int  oix = __shfl_xor(ix, m, 64);
            if (ov < v || (ov == v && oix < ix)) { v = ov; ix = oix; }
        }
        if (l15 == 0) {
            const int rl = wm * 64 + (tt_ >> 2) * 16 + l4 * 4 + (tt_ & 3);
            rv[rl * 2 + wn] = v;
            ri[rl * 2 + wn] = ix;
        }
    }
    __syncthreads();
    if (tid < 256) {
        float v0 = rv[tid * 2], v1 = rv[tid * 2 + 1];
        int   i0 = ri[tid * 2], i1 = ri[tid * 2 + 1];
        int ib = (v1 < v0 || (v1 == v0 && i1 < i0)) ? i1 : i0;
        flat_ind[row0 + tid] = ib;
        // wave-aggregated histogram (skew-proof)
        unsigned long long pending = ~0ULL;
        while (pending) {
            int leader = __ffsll((long long)pending) - 1;
            int lind = __shfl(ib, leader, 64);
            unsigned long long same = __ballot(ib == lind);
            if ((tid & 63) == leader) atomicAdd(&cnt[lind], (int)__popcll(same));
            pending &= ~same;
        }
    }
}

// ---------------------------------------------------------------------------
// scan: exclusive prefix sum over 2048 counts -> offsets, cursor
// ---------------------------------------------------------------------------
__global__ __launch_bounds__(256) void scan_kernel(
    const int* __restrict__ cnt, int* __restrict__ offs, int* __restrict__ cursor)
{
    __shared__ int ps[256];
    const int t = threadIdx.x;
    int pre[8], s = 0;
    #pragma unroll
    for (int j = 0; j < 8; ++j) { pre[j] = s; s += cnt[t * 8 + j]; }
    ps[t] = s;
    __syncthreads();
    for (int off = 1; off < 256; off <<= 1) {
        int v = (t >= off) ? ps[t - off] : 0;
        __syncthreads();
        ps[t] += v;
        __syncthreads();
    }
    int ex = (t > 0) ? ps[t - 1] : 0;
    #pragma unroll
    for (int j = 0; j < 8; ++j) {
        offs[t * 8 + j]   = ex + pre[j];
        cursor[t * 8 + j] = ex + pre[j];
    }
}

// ---------------------------------------------------------------------------
// assign: counting-sort placement with wave-aggregated cursor atomics.
// ---------------------------------------------------------------------------
__global__ __launch_bounds__(256) void assign_kernel(
    const int* __restrict__ flat_ind, int* __restrict__ cursor,
    int* __restrict__ rowlist, int* __restrict__ codesorted)
{
    const int i    = blockIdx.x * 256 + threadIdx.x;
    const int lane = threadIdx.x & 63;
    const int ind  = flat_ind[i];
    int pos = 0;
    unsigned long long pending = ~0ULL;
    while (pending) {
        int leader = __ffsll((long long)pending) - 1;
        int lind = __shfl(ind, leader, 64);
        unsigned long long same = __ballot(ind == lind);
        if (ind == lind) {
            int base = 0;
            if (lane == leader) base = atomicAdd(&cursor[lind], (int)__popcll(same));
            base = __shfl(base, leader, 64);
            pos = base + (int)__popcll(same & ((1ULL << lane) - 1ULL));
        }
        pending &= ~same;
    }
    rowlist[pos] = i;
    codesorted[pos] = ind;
}

// ---------------------------------------------------------------------------
// codesum: chunked segmented reduction over the sorted rowlist.
// ---------------------------------------------------------------------------
__global__ __launch_bounds__(256) void codesum_kernel(
    const float* __restrict__ x, const int* __restrict__ rowlist,
    const int* __restrict__ codesorted, float* __restrict__ sums)
{
    const int p0 = blockIdx.x * 64;
    __shared__ int rows[64], codes[64];
    if (threadIdx.x < 64) {
        rows[threadIdx.x]  = rowlist[p0 + threadIdx.x];
        codes[threadIdx.x] = codesorted[p0 + threadIdx.x];
    }
    __syncthreads();
    const int d = threadIdx.x;
    float acc = 0.f;
    int cur = codes[0];
    #pragma unroll 4
    for (int r = 0; r < 64; ++r) {
        const int c = codes[r];
        if (c != cur) {
            atomicAdd(&sums[(size_t)cur * DIM + d], acc);
            acc = 0.f; cur = c;
        }
        acc += x[(size_t)rows[r] * DIM + d];
    }
    atomicAdd(&sums[(size_t)cur * DIM + d], acc);
}

// ---------------------------------------------------------------------------
// finalize: EMA update outputs
// ---------------------------------------------------------------------------
__global__ __launch_bounds__(256) void finalize_kernel(
    const float* __restrict__ embed_sum, const float* __restrict__ usage,
    const float* __restrict__ sums, const int* __restrict__ cnt,
    float* __restrict__ out_usage, float* __restrict__ out_es)
{
    const int k = blockIdx.x, d = threadIdx.x;
    out_es[k * DIM + d] = embed_sum[k * DIM + d] * DECAYF + sums[k * DIM + d] * (1.0f - DECAYF);
    if (d == 0)
        out_usage[k] = usage[k] * DECAYF + (float)cnt[k] * (1.0f - DECAYF);
}

// ---------------------------------------------------------------------------
// quantize: out_q = embed[flat_ind], out_ind = (float)flat_ind
// ---------------------------------------------------------------------------
__global__ __launch_bounds__(256) void quantize_kernel(
    const float* __restrict__ embed, const int* __restrict__ flat_ind,
    float* __restrict__ out_q, float* __restrict__ out_ind_f, int N)
{
    int i = blockIdx.x * 256 + threadIdx.x;   // over N*64 float4s
    int row = i >> 6, c4 = i & 63;
    int ind = flat_ind[row];
    ((f32x4*)out_q)[i] = ((const f32x4*)embed)[ind * 64 + c4];
    if (i < N) out_ind_f[i] = (float)flat_ind[i];
}

extern "C" void kernel_launch(void* const* d_in, const int* in_sizes, int n_in,
                              void* d_out, int out_size, void* d_ws, size_t ws_size,
                              hipStream_t stream)
{
    const float* hs        = (const float*)d_in[0];
    const float* embed_sum = (const float*)d_in[1];
    const float* usage     = (const float*)d_in[2];
    const int N = in_sizes[0] / DIM;   // 65536

    float* ws_f      = (float*)d_ws;
    float* embed     = ws_f;                         // K*D f32
    float* e2        = embed + KCODES * DIM;         // K
    float* sums      = e2 + KCODES;                  // K*D f32
    f16*   eh        = (f16*)(sums + KCODES * DIM);  // K*D f16
    f16*   el        = eh + KCODES * DIM;            // K*D f16
    int*   cnt       = (int*)(el + KCODES * DIM);    // K
    int*   offs      = cnt + KCODES;                 // K
    int*   cursor    = offs + KCODES;                // K
    int*   rowlist   = cursor + KCODES;              // N
    int*   codesorted= rowlist + N;                  // N
    int*   flat_ind  = codesorted + N;               // N

    float* out_q     = (float*)d_out;                // N*D
    float* out_ind   = out_q + (size_t)N * DIM;      // N
    float* out_usage = out_ind + N;                  // K
    float* out_es    = out_usage + KCODES;           // K*D

    // xh/xl live in the out_q region (exactly N*D*4B); quantize overwrites later
    f16* xh = (f16*)out_q;
    f16* xl = xh + (size_t)N * DIM;

    hipMemsetAsync(cnt, 0, KCODES * sizeof(int), stream);
    hipMemsetAsync(sums, 0, (size_t)KCODES * DIM * sizeof(float), stream);

    split_x_kernel<<<(N * DIM / 8 + 255) / 256, 256, 0, stream>>>(hs, xh, xl, N * DIM / 8);
    prep_embed_kernel<<<KCODES, 256, 0, stream>>>(embed_sum, usage, embed, eh, el, e2);
    argmin_kernel<<<N / 256, 512, 0, stream>>>(xh, xl, eh, el, e2, flat_ind, cnt);
    scan_kernel<<<1, 256, 0, stream>>>(cnt, offs, cursor);
    assign_kernel<<<N / 256, 256, 0, stream>>>(flat_ind, cursor, rowlist, codesorted);
    codesum_kernel<<<N / 64, 256, 0, stream>>>(hs, rowlist, codesorted, sums);
    finalize_kernel<<<KCODES, 256, 0, stream>>>(embed_sum, usage, sums, cnt, out_usage, out_es);
    quantize_kernel<<<N * DIM / 4 / 256, 256, 0, stream>>>(embed, flat_ind, out_q, out_ind, N);
}

// Round 7
// 288.963 us; speedup vs baseline: 5.7931x; 1.0406x over previous
//
#include <hip/hip_runtime.h>

#define EPSF 1e-5f
#define DECAYF 0.99f
#define KCODES 2048
#define DIM 256
#define CC 64          // 8 code-tiles x 8 d-chunks of 32

typedef _Float16 f16;
typedef f16 f16x8 __attribute__((ext_vector_type(8)));
typedef float f32x4 __attribute__((ext_vector_type(4)));

#define MFMA16(A, B, C) __builtin_amdgcn_mfma_f32_16x16x32_f16(A, B, C, 0, 0, 0)

#define OFF_AH 0
#define OFF_AL 16384
#define OFF_BH 32768
#define OFF_BL 49152

__device__ __forceinline__ void gload_lds16(const void* g, void* l) {
    __builtin_amdgcn_global_load_lds(
        (const __attribute__((address_space(1))) void*)g,
        (__attribute__((address_space(3))) void*)l, 16, 0, 0);
}

// ---------------------------------------------------------------------------
// split_x: xh = (f16)x, xl = (f16)(x - xh)
// ---------------------------------------------------------------------------
__global__ __launch_bounds__(256) void split_x_kernel(
    const float* __restrict__ x, f16* __restrict__ xh, f16* __restrict__ xl, int n8)
{
    int i = blockIdx.x * 256 + threadIdx.x;
    if (i >= n8) return;
    f32x4 v0 = ((const f32x4*)x)[2 * i];
    f32x4 v1 = ((const f32x4*)x)[2 * i + 1];
    f16x8 h, l;
    #pragma unroll
    for (int t = 0; t < 4; ++t) {
        f16 h0 = (f16)v0[t]; h[t] = h0; l[t] = (f16)(v0[t] - (float)h0);
        f16 h1 = (f16)v1[t]; h[t + 4] = h1; l[t + 4] = (f16)(v1[t] - (float)h1);
    }
    ((f16x8*)xh)[i] = h;
    ((f16x8*)xl)[i] = l;
}

// ---------------------------------------------------------------------------
// prep: embed = embed_sum / clamp(usage); e2 = ||embed||^2; eh/el f16 split
// ---------------------------------------------------------------------------
__global__ __launch_bounds__(256) void prep_embed_kernel(
    const float* __restrict__ embed_sum, const float* __restrict__ usage,
    float* __restrict__ embed, f16* __restrict__ eh, f16* __restrict__ el,
    float* __restrict__ e2)
{
    int k = blockIdx.x;
    int d = threadIdx.x;
    float inv = 1.0f / fmaxf(usage[k], EPSF);
    float e = embed_sum[k * DIM + d] * inv;
    embed[k * DIM + d] = e;
    float ec = fminf(fmaxf(e, -65000.0f), 65000.0f);
    f16 h = (f16)ec;
    f16 l = (f16)(ec - (float)h);
    eh[k * DIM + d] = h;
    el[k * DIM + d] = l;
    float sq = e * e;
    #pragma unroll
    for (int off = 32; off > 0; off >>= 1) sq += __shfl_down(sq, off, 64);
    __shared__ float ws[4];
    if ((threadIdx.x & 63) == 0) ws[threadIdx.x >> 6] = sq;
    __syncthreads();
    if (threadIdx.x == 0) e2[k] = ws[0] + ws[1] + ws[2] + ws[3];
}

// ---------------------------------------------------------------------------
// argmin: fragment-shared pipelined f16 GEMM-argmin, de-serialized.
// BM=256 x BN=256, 8 waves (4M x 2N, wave tile 64x128), 16x16x32 f16.
// Per 32-d chunk: ONE region {24 ds_read_b128 + 96 MFMA}, compiler-scheduled
// (fine-grained lgkmcnt overlap), ONE raw s_barrier per chunk. Stage of the
// next chunk (opposite-parity buffer) issues early so its HBM latency hides
// under the whole chunk; vmcnt(0) at the top is free in steady state.
// ---------------------------------------------------------------------------
__global__ __launch_bounds__(512, 2) void argmin_kernel(
    const f16* __restrict__ xh, const f16* __restrict__ xl,
    const f16* __restrict__ eh, const f16* __restrict__ el,
    const float* __restrict__ e2, int* __restrict__ flat_ind, int* __restrict__ cnt)
{
    __shared__ __align__(1024) char lds[2 * 65536 + 8192];
    float* e2s = (float*)(lds + 131072);

    const int tid  = threadIdx.x;
    const int w    = tid >> 6, lane = tid & 63;
    const int l15  = lane & 15, l4 = lane >> 4;
    const int wm   = w >> 1, wn = w & 1;
    const int row0 = blockIdx.x * 256;
    const int gsw  = (lane & 3) ^ ((lane >> 3) & 3);     // write-side inverse swizzle
    const int lq   = lane >> 2;
    const int rslot = (l4 ^ ((l15 >> 1) & 3)) * 16;      // read-side swizzled slot

    f32x4 acc[4][8];
    float best[16];
    int   bidx[16];
    #pragma unroll
    for (int t = 0; t < 16; ++t) { best[t] = 3.4e38f; bidx[t] = 0; }

    auto stageU = [&](const f16* rowbase, int koff, char* unit) {
        #pragma unroll
        for (int q = 0; q < 2; ++q) {
            const int r = w * 32 + q * 16 + lq;
            gload_lds16(rowbase + (size_t)r * DIM + koff + gsw * 8,
                        unit + w * 2048 + q * 1024 + lane * 16);
        }
    };

    // ---- prologue: e2 stash, then chunk 0's four units
    ((f32x4*)e2s)[tid] = ((const f32x4*)e2)[tid];
    stageU(xh + (size_t)row0 * DIM, 0, lds + OFF_AH);
    stageU(xl + (size_t)row0 * DIM, 0, lds + OFF_AL);
    stageU(eh, 0, lds + OFF_BH);
    stageU(el, 0, lds + OFF_BL);

    for (int cc = 0; cc < CC; ++cc) {
        char* buf  = lds + (cc & 1) * 65536;
        char* nbuf = lds + ((cc + 1) & 1) * 65536;
        const int ct = cc >> 3, sd = cc & 7;
        const int nn = cc + 1;
        const int nct = nn >> 3, nsd = nn & 7;
        const bool more = (nn < CC);

        if (sd == 0) {
            #pragma unroll
            for (int i = 0; i < 4; ++i)
                #pragma unroll
                for (int j = 0; j < 8; ++j)
                    acc[i][j] = (f32x4){0.f, 0.f, 0.f, 0.f};
        }

        // loads issued last chunk (filling buf) must be complete everywhere:
        // own-wave via vmcnt(0) (free: issued ~a full chunk ago), cross-wave
        // via the barrier. sched_barrier stops reads hoisting above it.
        asm volatile("s_waitcnt vmcnt(0)" ::: "memory");
        __builtin_amdgcn_s_barrier();
        __builtin_amdgcn_sched_barrier(0);

        // issue next chunk's staging early -> latency hides under this chunk
        if (more) {
            stageU(xh + (size_t)row0 * DIM, nsd * 32, nbuf + OFF_AH);
            stageU(xl + (size_t)row0 * DIM, nsd * 32, nbuf + OFF_AL);
            stageU(eh + (size_t)(nct * 256) * DIM, nsd * 32, nbuf + OFF_BH);
            stageU(el + (size_t)(nct * 256) * DIM, nsd * 32, nbuf + OFF_BL);
        }

        // one region: reads + MFMA, compiler-interleaved (no lgkmcnt(0) pin)
        f16x8 ah[4], al[4], bh[8], bl[8];
        #pragma unroll
        for (int i = 0; i < 4; ++i)
            ah[i] = *(const f16x8*)(buf + OFF_AH + (wm * 64 + i * 16 + l15) * 64 + rslot);
        #pragma unroll
        for (int j = 0; j < 8; ++j)
            bh[j] = *(const f16x8*)(buf + OFF_BH + (wn * 128 + j * 16 + l15) * 64 + rslot);
        #pragma unroll
        for (int i = 0; i < 4; ++i)
            al[i] = *(const f16x8*)(buf + OFF_AL + (wm * 64 + i * 16 + l15) * 64 + rslot);

        #pragma unroll
        for (int i = 0; i < 4; ++i)
            #pragma unroll
            for (int j = 0; j < 8; ++j)
                acc[i][j] = MFMA16(ah[i], bh[j], acc[i][j]);
        #pragma unroll
        for (int i = 0; i < 4; ++i)
            #pragma unroll
            for (int j = 0; j < 8; ++j)
                acc[i][j] = MFMA16(al[i], bh[j], acc[i][j]);

        #pragma unroll
        for (int j = 0; j < 8; ++j)
            bl[j] = *(const f16x8*)(buf + OFF_BL + (wn * 128 + j * 16 + l15) * 64 + rslot);
        #pragma unroll
        for (int i = 0; i < 4; ++i)
            #pragma unroll
            for (int j = 0; j < 8; ++j)
                acc[i][j] = MFMA16(ah[i], bl[j], acc[i][j]);

        // fold argmin at end of each code-tile
        if (sd == 7) {
            const int cbase = ct * 256 + wn * 128;
            #pragma unroll
            for (int j = 0; j < 8; ++j) {
                const int col = cbase + j * 16 + l15;
                const float e2v = e2s[col];
                #pragma unroll
                for (int i = 0; i < 4; ++i)
                    #pragma unroll
                    for (int r = 0; r < 4; ++r) {
                        float m = fmaf(-2.0f, acc[i][j][r], e2v);
                        const int tt_ = i * 4 + r;
                        if (m < best[tt_]) { best[tt_] = m; bidx[tt_] = col; }
                    }
            }
        }
    }

    // ---- final reduce: 16 col-lanes, then 2 col-waves via LDS
    __syncthreads();
    float* rv = (float*)lds;
    int*   ri = (int*)(lds + 4096);
    #pragma unroll
    for (int tt_ = 0; tt_ < 16; ++tt_) {
        float v = best[tt_];
        int  ix = bidx[tt_];
        #pragma unroll
        for (int m = 1; m <= 8; m <<= 1) {
            float ov = __shfl_xor(v, m, 64);
            int  oix = __shfl_xor(ix, m, 64);
            if (ov < v || (ov == v && oix < ix)) { v = ov; ix = oix; }
        }
        if (l15 == 0) {
            const int rl = wm * 64 + (tt_ >> 2) * 16 + l4 * 4 + (tt_ & 3);
            rv[rl * 2 + wn] = v;
            ri[rl * 2 + wn] = ix;
        }
    }
    __syncthreads();
    if (tid < 256) {
        float v0 = rv[tid * 2], v1 = rv[tid * 2 + 1];
        int   i0 = ri[tid * 2], i1 = ri[tid * 2 + 1];
        int ib = (v1 < v0 || (v1 == v0 && i1 < i0)) ? i1 : i0;
        flat_ind[row0 + tid] = ib;
        // wave-aggregated histogram (skew-proof)
        unsigned long long pending = ~0ULL;
        while (pending) {
            int leader = __ffsll((long long)pending) - 1;
            int lind = __shfl(ib, leader, 64);
            unsigned long long same = __ballot(ib == lind);
            if ((tid & 63) == leader) atomicAdd(&cnt[lind], (int)__popcll(same));
            pending &= ~same;
        }
    }
}

// ---------------------------------------------------------------------------
// scan: exclusive prefix sum over 2048 counts -> offsets, cursor
// ---------------------------------------------------------------------------
__global__ __launch_bounds__(256) void scan_kernel(
    const int* __restrict__ cnt, int* __restrict__ offs, int* __restrict__ cursor)
{
    __shared__ int ps[256];
    const int t = threadIdx.x;
    int pre[8], s = 0;
    #pragma unroll
    for (int j = 0; j < 8; ++j) { pre[j] = s; s += cnt[t * 8 + j]; }
    ps[t] = s;
    __syncthreads();
    for (int off = 1; off < 256; off <<= 1) {
        int v = (t >= off) ? ps[t - off] : 0;
        __syncthreads();
        ps[t] += v;
        __syncthreads();
    }
    int ex = (t > 0) ? ps[t - 1] : 0;
    #pragma unroll
    for (int j = 0; j < 8; ++j) {
        offs[t * 8 + j]   = ex + pre[j];
        cursor[t * 8 + j] = ex + pre[j];
    }
}

// ---------------------------------------------------------------------------
// assign: counting-sort placement with wave-aggregated cursor atomics.
// ---------------------------------------------------------------------------
__global__ __launch_bounds__(256) void assign_kernel(
    const int* __restrict__ flat_ind, int* __restrict__ cursor,
    int* __restrict__ rowlist, int* __restrict__ codesorted)
{
    const int i    = blockIdx.x * 256 + threadIdx.x;
    const int lane = threadIdx.x & 63;
    const int ind  = flat_ind[i];
    int pos = 0;
    unsigned long long pending = ~0ULL;
    while (pending) {
        int leader = __ffsll((long long)pending) - 1;
        int lind = __shfl(ind, leader, 64);
        unsigned long long same = __ballot(ind == lind);
        if (ind == lind) {
            int base = 0;
            if (lane == leader) base = atomicAdd(&cursor[lind], (int)__popcll(same));
            base = __shfl(base, leader, 64);
            pos = base + (int)__popcll(same & ((1ULL << lane) - 1ULL));
        }
        pending &= ~same;
    }
    rowlist[pos] = i;
    codesorted[pos] = ind;
}

// ---------------------------------------------------------------------------
// codesum: chunked segmented reduction over the sorted rowlist.
// ---------------------------------------------------------------------------
__global__ __launch_bounds__(256) void codesum_kernel(
    const float* __restrict__ x, const int* __restrict__ rowlist,
    const int* __restrict__ codesorted, float* __restrict__ sums)
{
    const int p0 = blockIdx.x * 64;
    __shared__ int rows[64], codes[64];
    if (threadIdx.x < 64) {
        rows[threadIdx.x]  = rowlist[p0 + threadIdx.x];
        codes[threadIdx.x] = codesorted[p0 + threadIdx.x];
    }
    __syncthreads();
    const int d = threadIdx.x;
    float acc = 0.f;
    int cur = codes[0];
    #pragma unroll 4
    for (int r = 0; r < 64; ++r) {
        const int c = codes[r];
        if (c != cur) {
            atomicAdd(&sums[(size_t)cur * DIM + d], acc);
            acc = 0.f; cur = c;
        }
        acc += x[(size_t)rows[r] * DIM + d];
    }
    atomicAdd(&sums[(size_t)cur * DIM + d], acc);
}

// ---------------------------------------------------------------------------
// finalize: EMA update outputs
// ---------------------------------------------------------------------------
__global__ __launch_bounds__(256) void finalize_kernel(
    const float* __restrict__ embed_sum, const float* __restrict__ usage,
    const float* __restrict__ sums, const int* __restrict__ cnt,
    float* __restrict__ out_usage, float* __restrict__ out_es)
{
    const int k = blockIdx.x, d = threadIdx.x;
    out_es[k * DIM + d] = embed_sum[k * DIM + d] * DECAYF + sums[k * DIM + d] * (1.0f - DECAYF);
    if (d == 0)
        out_usage[k] = usage[k] * DECAYF + (float)cnt[k] * (1.0f - DECAYF);
}

// ---------------------------------------------------------------------------
// quantize: out_q = embed[flat_ind], out_ind = (float)flat_ind
// ---------------------------------------------------------------------------
__global__ __launch_bounds__(256) void quantize_kernel(
    const float* __restrict__ embed, const int* __restrict__ flat_ind,
    float* __restrict__ out_q, float* __restrict__ out_ind_f, int N)
{
    int i = blockIdx.x * 256 + threadIdx.x;   // over N*64 float4s
    int row = i >> 6, c4 = i & 63;
    int ind = flat_ind[row];
    ((f32x4*)out_q)[i] = ((const f32x4*)embed)[ind * 64 + c4];
    if (i < N) out_ind_f[i] = (float)flat_ind[i];
}

extern "C" void kernel_launch(void* const* d_in, const int* in_sizes, int n_in,
                              void* d_out, int out_size, void* d_ws, size_t ws_size,
                              hipStream_t stream)
{
    const float* hs        = (const float*)d_in[0];
    const float* embed_sum = (const float*)d_in[1];
    const float* usage     = (const float*)d_in[2];
    const int N = in_sizes[0] / DIM;   // 65536

    float* ws_f      = (float*)d_ws;
    float* embed     = ws_f;                         // K*D f32
    float* e2        = embed + KCODES * DIM;         // K
    float* sums      = e2 + KCODES;                  // K*D f32
    f16*   eh        = (f16*)(sums + KCODES * DIM);  // K*D f16
    f16*   el        = eh + KCODES * DIM;            // K*D f16
    int*   cnt       = (int*)(el + KCODES * DIM);    // K
    int*   offs      = cnt + KCODES;                 // K
    int*   cursor    = offs + KCODES;                // K
    int*   rowlist   = cursor + KCODES;              // N
    int*   codesorted= rowlist + N;                  // N
    int*   flat_ind  = codesorted + N;               // N

    float* out_q     = (float*)d_out;                // N*D
    float* out_ind   = out_q + (size_t)N * DIM;      // N
    float* out_usage = out_ind + N;                  // K
    float* out_es    = out_usage + KCODES;           // K*D

    // xh/xl live in the out_q region (exactly N*D*4B); quantize overwrites later
    f16* xh = (f16*)out_q;
    f16* xl = xh + (size_t)N * DIM;

    hipMemsetAsync(cnt, 0, KCODES * sizeof(int), stream);
    hipMemsetAsync(sums, 0, (size_t)KCODES * DIM * sizeof(float), stream);

    split_x_kernel<<<(N * DIM / 8 + 255) / 256, 256, 0, stream>>>(hs, xh, xl, N * DIM / 8);
    prep_embed_kernel<<<KCODES, 256, 0, stream>>>(embed_sum, usage, embed, eh, el, e2);
    argmin_kernel<<<N / 256, 512, 0, stream>>>(xh, xl, eh, el, e2, flat_ind, cnt);
    scan_kernel<<<1, 256, 0, stream>>>(cnt, offs, cursor);
    assign_kernel<<<N / 256, 256, 0, stream>>>(flat_ind, cursor, rowlist, codesorted);
    codesum_kernel<<<N / 64, 256, 0, stream>>>(hs, rowlist, codesorted, sums);
    finalize_kernel<<<KCODES, 256, 0, stream>>>(embed_sum, usage, sums, cnt, out_usage, out_es);
    quantize_kernel<<<N * DIM / 4 / 256, 256, 0, stream>>>(embed, flat_ind, out_q, out_ind, N);
}